// Round 1
// baseline (1138.294 us; speedup 1.0000x reference)
//
#include <hip/hip_runtime.h>
#include <math.h>

// Problem constants (from reference)
#define NB   4
#define SEQ  2048
#define NH   12
#define HD   64      // head_dim
#define CIN  2304    // 3*768 floats per token row
#define TQ   64      // q rows per block
#define TM   64      // k/v rows per chunk
#define KSTR 68      // padded stride (floats) for transposed Q/K tiles (mult of 4)
#define VSTR 64      // stride for V / row-major tiles

// One block = 256 threads = 4 waves. Handles TQ query rows of one (b,h).
// Thread map for compute: ty = tid/16 (0..15) -> 4 q-rows ty*4+r
//                         tx = tid%16 (0..15) -> 4 cols  tx*4+c
// Row-softmax state replicated across the 16-lane tx-group (shfl_xor <16).
__global__ __launch_bounds__(256, 3)
void fused_ln_attn_kernel(const float* __restrict__ QKV,
                          const float* __restrict__ q_scale,
                          const float* __restrict__ q_bias,
                          const float* __restrict__ k_scale,
                          const float* __restrict__ k_bias,
                          float* __restrict__ out)
{
    // Qt[dd][q]: transposed normalized-Q tile (scale 1/8 folded in)
    __shared__ __align__(16) float Qt[HD * KSTR];
    // KP: first Kt[dd][m] (transposed normalized K), then reused as Ps[q][m]
    __shared__ __align__(16) float KP[HD * KSTR];
    // Vs[m][dd]: raw V chunk
    __shared__ __align__(16) float Vs[TM * VSTR];

    const int tid  = threadIdx.x;
    const int lane = tid & 63;   // = dd during load/layernorm
    const int wv   = tid >> 6;   // wave id 0..3
    const int ty   = tid >> 4;   // 0..15
    const int tx   = tid & 15;   // 0..15

    const int qt = blockIdx.x;
    const int h  = blockIdx.y;
    const int b  = blockIdx.z;
    const int q0 = qt * TQ;

    const float qs = q_scale[lane], qb = q_bias[lane];
    const float ks = k_scale[lane], kb = k_bias[lane];

    // ---- load + layernorm Q tile, store transposed into Qt ----
    // wave wv handles rows [wv*16, wv*16+16), batched 4 rows -> one b128 write
    for (int g = 0; g < 4; ++g) {
        float qn[4];
        #pragma unroll
        for (int j = 0; j < 4; ++j) {
            int row = wv * 16 + g * 4 + j;
            int n = q0 + row;
            float v = QKV[(size_t)(b * SEQ + n) * CIN + h * 64 + lane];
            float s = v;
            #pragma unroll
            for (int off = 32; off >= 1; off >>= 1) s += __shfl_xor(s, off);
            float mean = s * 0.015625f;
            float dv = v - mean;
            float s2 = dv * dv;
            #pragma unroll
            for (int off = 32; off >= 1; off >>= 1) s2 += __shfl_xor(s2, off);
            float rstd = rsqrtf(s2 * 0.015625f + 1e-6f);
            qn[j] = (dv * rstd * qs + qb) * 0.125f;  // fold softmax scale into Q
        }
        *(float4*)&Qt[lane * KSTR + wv * 16 + g * 4] =
            make_float4(qn[0], qn[1], qn[2], qn[3]);
    }

    float o[4][4] = {};          // O accumulator: rows ty*4+r, cols tx*4+c
    float m_r[4], l_r[4];
    #pragma unroll
    for (int r = 0; r < 4; ++r) { m_r[r] = -INFINITY; l_r[r] = 0.0f; }

    for (int mc = 0; mc < SEQ / TM; ++mc) {
        __syncthreads();  // previous chunk's PV reads of KP/Vs complete

        // ---- load K chunk (layernorm, transposed into KP) + V chunk ----
        for (int g = 0; g < 4; ++g) {
            float kn[4];
            #pragma unroll
            for (int j = 0; j < 4; ++j) {
                int row = wv * 16 + g * 4 + j;
                int m = mc * TM + row;
                size_t gb = (size_t)(b * SEQ + m) * CIN + h * 64 + lane;
                float kv = QKV[gb + 768];
                float vv = QKV[gb + 1536];
                float s = kv;
                #pragma unroll
                for (int off = 32; off >= 1; off >>= 1) s += __shfl_xor(s, off);
                float mean = s * 0.015625f;
                float dv = kv - mean;
                float s2 = dv * dv;
                #pragma unroll
                for (int off = 32; off >= 1; off >>= 1) s2 += __shfl_xor(s2, off);
                float rstd = rsqrtf(s2 * 0.015625f + 1e-6f);
                kn[j] = dv * rstd * ks + kb;
                Vs[row * VSTR + lane] = vv;
            }
            *(float4*)&KP[lane * KSTR + wv * 16 + g * 4] =
                make_float4(kn[0], kn[1], kn[2], kn[3]);
        }
        __syncthreads();

        // ---- S = (Q/8) K^T : outer product over dd, conflict-free b128 reads
        float sa[4][4] = {};
        #pragma unroll 16
        for (int dd = 0; dd < HD; ++dd) {
            float4 qv = *(const float4*)&Qt[dd * KSTR + ty * 4];
            float4 kv = *(const float4*)&KP[dd * KSTR + tx * 4];
            float qa[4] = {qv.x, qv.y, qv.z, qv.w};
            float ka[4] = {kv.x, kv.y, kv.z, kv.w};
            #pragma unroll
            for (int r = 0; r < 4; ++r)
                #pragma unroll
                for (int c = 0; c < 4; ++c)
                    sa[r][c] = fmaf(qa[r], ka[c], sa[r][c]);
        }
        __syncthreads();  // all Kt reads done -> KP reusable as Ps

        // ---- online softmax (per q-row, reduced across 16-lane tx group) ----
        #pragma unroll
        for (int r = 0; r < 4; ++r) {
            float lm = fmaxf(fmaxf(sa[r][0], sa[r][1]), fmaxf(sa[r][2], sa[r][3]));
            #pragma unroll
            for (int off = 1; off < 16; off <<= 1) lm = fmaxf(lm, __shfl_xor(lm, off));
            float mnew = fmaxf(m_r[r], lm);
            float alpha = __expf(m_r[r] - mnew);   // exp(-inf)=0 on first chunk
            float p0 = __expf(sa[r][0] - mnew);
            float p1 = __expf(sa[r][1] - mnew);
            float p2 = __expf(sa[r][2] - mnew);
            float p3 = __expf(sa[r][3] - mnew);
            float ls = (p0 + p1) + (p2 + p3);
            #pragma unroll
            for (int off = 1; off < 16; off <<= 1) ls += __shfl_xor(ls, off);
            m_r[r] = mnew;
            l_r[r] = l_r[r] * alpha + ls;
            o[r][0] *= alpha; o[r][1] *= alpha; o[r][2] *= alpha; o[r][3] *= alpha;
            *(float4*)&KP[(ty * 4 + r) * KSTR + tx * 4] =
                make_float4(p0, p1, p2, p3);
        }
        __syncthreads();  // Ps visible

        // ---- O += P V ----
        #pragma unroll 4
        for (int m4 = 0; m4 < TM; m4 += 4) {
            float pa[4][4];
            #pragma unroll
            for (int r = 0; r < 4; ++r) {
                float4 t = *(const float4*)&KP[(ty * 4 + r) * KSTR + m4];
                pa[r][0] = t.x; pa[r][1] = t.y; pa[r][2] = t.z; pa[r][3] = t.w;
            }
            #pragma unroll
            for (int j = 0; j < 4; ++j) {
                float4 vv = *(const float4*)&Vs[(m4 + j) * VSTR + tx * 4];
                #pragma unroll
                for (int r = 0; r < 4; ++r) {
                    o[r][0] = fmaf(pa[r][j], vv.x, o[r][0]);
                    o[r][1] = fmaf(pa[r][j], vv.y, o[r][1]);
                    o[r][2] = fmaf(pa[r][j], vv.z, o[r][2]);
                    o[r][3] = fmaf(pa[r][j], vv.w, o[r][3]);
                }
            }
        }
    }

    // ---- epilogue: normalize by l and store [B,H,N,d] ----
    #pragma unroll
    for (int r = 0; r < 4; ++r) {
        float inv = 1.0f / l_r[r];
        int n = q0 + ty * 4 + r;
        float4 res = make_float4(o[r][0] * inv, o[r][1] * inv,
                                 o[r][2] * inv, o[r][3] * inv);
        *(float4*)&out[(size_t)((b * NH + h) * SEQ + n) * 64 + tx * 4] = res;
    }
}

extern "C" void kernel_launch(void* const* d_in, const int* in_sizes, int n_in,
                              void* d_out, int out_size, void* d_ws, size_t ws_size,
                              hipStream_t stream) {
    const float* QKV     = (const float*)d_in[0];
    const float* q_scale = (const float*)d_in[1];
    const float* q_bias  = (const float*)d_in[2];
    const float* k_scale = (const float*)d_in[3];
    const float* k_bias  = (const float*)d_in[4];
    float* out = (float*)d_out;

    dim3 grid(SEQ / TQ, NH, NB);  // 32 x 12 x 4 = 1536 blocks
    fused_ln_attn_kernel<<<grid, 256, 0, stream>>>(
        QKV, q_scale, q_bias, k_scale, k_bias, out);
}

// Round 2
// 265.118 us; speedup vs baseline: 4.2935x; 4.2935x over previous
//
#include <hip/hip_runtime.h>
#include <math.h>

// Problem constants
#define NB   4
#define SEQ  2048
#define NH   12
#define CIN  2304    // 3*768 floats per token
#define TQ   64      // q rows per block
#define TM   64      // kv rows per chunk
#define LSTR 72      // f16 LDS row stride: 36 dwords == 4 (mod 32) -> conflict-free b128 phases

typedef _Float16 half8 __attribute__((ext_vector_type(8)));
typedef _Float16 half4 __attribute__((ext_vector_type(4)));
typedef float    f32x4 __attribute__((ext_vector_type(4)));

// Block = 256 thr = 4 waves. Each wave owns a 16-q strip.
// S^T[kv][q] = K(row-major A) x Q(row-major, as B): C-layout row=kv, col=q
//   -> per lane ONE q-column: softmax reduce = local + shfl_xor(16,32).
// O^T[d][q]  = Vt(row-major A) x Pq(row-major, as B).
__global__ __launch_bounds__(256, 4)
void fused_ln_attn_mfma(const float* __restrict__ QKV,
                        const float* __restrict__ q_scale,
                        const float* __restrict__ q_bias,
                        const float* __restrict__ k_scale,
                        const float* __restrict__ k_bias,
                        float* __restrict__ out)
{
    __shared__ __align__(16) _Float16 Qa[TQ * LSTR];  // Q[q][d]   (LN'd, x0.125)
    __shared__ __align__(16) _Float16 Ka[TM * LSTR];  // K[kv][d]  (LN'd)
    __shared__ __align__(16) _Float16 Vt[64 * LSTR];  // V^T[d][kv]
    __shared__ __align__(16) _Float16 Pq[TQ * LSTR];  // P[q][kv]  (wave-private strips)

    const int tid  = threadIdx.x;
    const int L    = tid & 63;
    const int wv   = tid >> 6;   // wave 0..3
    const int n16  = L & 15;
    const int quad = L >> 4;
    const int r4   = L >> 2;     // staging: row within 16
    const int c4   = L & 3;      // staging: 16-float column group

    const int qt = blockIdx.x, h = blockIdx.y, b = blockIdx.z;
    const int q0 = qt * TQ;

    const float4* QKV4 = (const float4*)QKV;

    // per-lane scale/bias for K LN (16 consecutive d starting at c4*16)
    float4 ksr[4], kbr[4];
    #pragma unroll
    for (int i = 0; i < 4; ++i) {
        ksr[i] = ((const float4*)k_scale)[c4 * 4 + i];
        kbr[i] = ((const float4*)k_bias)[c4 * 4 + i];
    }

    // ---------- Q prologue: load 16 floats/lane, LN, fold 1/8, store f16 ----------
    {
        const int row = wv * 16 + r4;
        size_t gb = (size_t)(b * SEQ + q0 + row) * 576 + h * 16 + c4 * 4;
        float4 x[4];
        #pragma unroll
        for (int i = 0; i < 4; ++i) x[i] = QKV4[gb + i];
        float s = 0.f, s2 = 0.f;
        #pragma unroll
        for (int i = 0; i < 4; ++i) {
            s  += x[i].x + x[i].y + x[i].z + x[i].w;
            s2 += x[i].x*x[i].x + x[i].y*x[i].y + x[i].z*x[i].z + x[i].w*x[i].w;
        }
        s  += __shfl_xor(s, 1);  s  += __shfl_xor(s, 2);
        s2 += __shfl_xor(s2, 1); s2 += __shfl_xor(s2, 2);
        float mu   = s * 0.015625f;
        float var  = s2 * 0.015625f - mu * mu;
        float rstd = rsqrtf(var + 1e-6f);
        float nb0  = -mu * rstd;
        half8 h0, h1;
        #pragma unroll
        for (int i = 0; i < 4; ++i) {
            float4 qs = ((const float4*)q_scale)[c4 * 4 + i];
            float4 qb = ((const float4*)q_bias)[c4 * 4 + i];
            float e0 = (fmaf(x[i].x, rstd, nb0) * qs.x + qb.x) * 0.125f;
            float e1 = (fmaf(x[i].y, rstd, nb0) * qs.y + qb.y) * 0.125f;
            float e2 = (fmaf(x[i].z, rstd, nb0) * qs.z + qb.z) * 0.125f;
            float e3 = (fmaf(x[i].w, rstd, nb0) * qs.w + qb.w) * 0.125f;
            if (i < 2) { h0[i*4+0]=(_Float16)e0; h0[i*4+1]=(_Float16)e1; h0[i*4+2]=(_Float16)e2; h0[i*4+3]=(_Float16)e3; }
            else { int j=(i-2)*4; h1[j+0]=(_Float16)e0; h1[j+1]=(_Float16)e1; h1[j+2]=(_Float16)e2; h1[j+3]=(_Float16)e3; }
        }
        *(half8*)&Qa[row * LSTR + c4 * 16]     = h0;
        *(half8*)&Qa[row * LSTR + c4 * 16 + 8] = h1;
    }

    f32x4 oacc[4] = {{0.f,0.f,0.f,0.f},{0.f,0.f,0.f,0.f},{0.f,0.f,0.f,0.f},{0.f,0.f,0.f,0.f}};
    float m_st = -INFINITY, l_st = 0.f;

    // fragment LDS element offsets
    const int aoff = n16 * LSTR + quad * 8;               // A frags: + mt*16*LSTR + ks*32
    const int boff = (wv * 16 + n16) * LSTR + quad * 8;   // B frags: + ks*32

    for (int mc = 0; mc < SEQ / TM; ++mc) {
        __syncthreads();  // prev chunk's frag reads of Ka/Vt complete

        // ---- K staging: LN'd f16 into Ka[kv][d] ----
        {
            const int row = wv * 16 + r4;
            size_t gb = (size_t)(b * SEQ + mc * TM + row) * 576 + 192 + h * 16 + c4 * 4;
            float4 x[4];
            #pragma unroll
            for (int i = 0; i < 4; ++i) x[i] = QKV4[gb + i];
            float s = 0.f, s2 = 0.f;
            #pragma unroll
            for (int i = 0; i < 4; ++i) {
                s  += x[i].x + x[i].y + x[i].z + x[i].w;
                s2 += x[i].x*x[i].x + x[i].y*x[i].y + x[i].z*x[i].z + x[i].w*x[i].w;
            }
            s  += __shfl_xor(s, 1);  s  += __shfl_xor(s, 2);
            s2 += __shfl_xor(s2, 1); s2 += __shfl_xor(s2, 2);
            float mu   = s * 0.015625f;
            float var  = s2 * 0.015625f - mu * mu;
            float rstd = rsqrtf(var + 1e-6f);
            float nb0  = -mu * rstd;
            half8 h0, h1;
            #pragma unroll
            for (int i = 0; i < 4; ++i) {
                float e0 = fmaf(x[i].x, rstd, nb0) * ksr[i].x + kbr[i].x;
                float e1 = fmaf(x[i].y, rstd, nb0) * ksr[i].y + kbr[i].y;
                float e2 = fmaf(x[i].z, rstd, nb0) * ksr[i].z + kbr[i].z;
                float e3 = fmaf(x[i].w, rstd, nb0) * ksr[i].w + kbr[i].w;
                if (i < 2) { h0[i*4+0]=(_Float16)e0; h0[i*4+1]=(_Float16)e1; h0[i*4+2]=(_Float16)e2; h0[i*4+3]=(_Float16)e3; }
                else { int j=(i-2)*4; h1[j+0]=(_Float16)e0; h1[j+1]=(_Float16)e1; h1[j+2]=(_Float16)e2; h1[j+3]=(_Float16)e3; }
            }
            *(half8*)&Ka[row * LSTR + c4 * 16]     = h0;
            *(half8*)&Ka[row * LSTR + c4 * 16 + 8] = h1;
        }

        // ---- V staging: transposed f16 into Vt[d][kv] (lane = d) ----
        {
            const float* gv = QKV + (size_t)(b * SEQ + mc * TM + wv * 16) * CIN + 1536 + h * 64 + L;
            float vv[16];
            #pragma unroll
            for (int r = 0; r < 16; ++r) vv[r] = gv[(size_t)r * CIN];
            half8 va0, va1;
            #pragma unroll
            for (int r = 0; r < 8; ++r) { va0[r] = (_Float16)vv[r]; va1[r] = (_Float16)vv[r + 8]; }
            *(half8*)&Vt[L * LSTR + wv * 16]     = va0;
            *(half8*)&Vt[L * LSTR + wv * 16 + 8] = va1;
        }
        __syncthreads();  // staging visible

        // ---- S^T = K x Q^T : 8 MFMAs ----
        f32x4 sacc[4] = {{0.f,0.f,0.f,0.f},{0.f,0.f,0.f,0.f},{0.f,0.f,0.f,0.f},{0.f,0.f,0.f,0.f}};
        #pragma unroll
        for (int ks = 0; ks < 2; ++ks) {
            half8 bq = *(half8*)&Qa[boff + ks * 32];
            #pragma unroll
            for (int mt = 0; mt < 4; ++mt) {
                half8 ak = *(half8*)&Ka[aoff + mt * 16 * LSTR + ks * 32];
                sacc[mt] = __builtin_amdgcn_mfma_f32_16x16x32_f16(ak, bq, sacc[mt], 0, 0, 0);
            }
        }

        // ---- online softmax: per lane = one q column, 16 kv values ----
        float mx = sacc[0][0];
        #pragma unroll
        for (int mt = 0; mt < 4; ++mt)
            #pragma unroll
            for (int r = 0; r < 4; ++r) mx = fmaxf(mx, sacc[mt][r]);
        mx = fmaxf(mx, __shfl_xor(mx, 16));
        mx = fmaxf(mx, __shfl_xor(mx, 32));
        float mnew  = fmaxf(m_st, mx);
        float alpha = __expf(m_st - mnew);
        float ls = 0.f;
        #pragma unroll
        for (int mt = 0; mt < 4; ++mt) {
            float p0 = __expf(sacc[mt][0] - mnew);
            float p1 = __expf(sacc[mt][1] - mnew);
            float p2 = __expf(sacc[mt][2] - mnew);
            float p3 = __expf(sacc[mt][3] - mnew);
            ls += (p0 + p1) + (p2 + p3);
            half4 hp; hp[0]=(_Float16)p0; hp[1]=(_Float16)p1; hp[2]=(_Float16)p2; hp[3]=(_Float16)p3;
            *(half4*)&Pq[(wv * 16 + n16) * LSTR + mt * 16 + quad * 4] = hp;  // kv = mt*16+quad*4+r
        }
        ls += __shfl_xor(ls, 16);
        ls += __shfl_xor(ls, 32);
        l_st = l_st * alpha + ls;
        m_st = mnew;
        #pragma unroll
        for (int mt = 0; mt < 4; ++mt)
            #pragma unroll
            for (int r = 0; r < 4; ++r) oacc[mt][r] *= alpha;

        // ---- O^T += Vt x Pq^T : 8 MFMAs (Pq wave-private: no barrier needed) ----
        #pragma unroll
        for (int ks = 0; ks < 2; ++ks) {
            half8 bp = *(half8*)&Pq[boff + ks * 32];
            #pragma unroll
            for (int mt = 0; mt < 4; ++mt) {
                half8 av = *(half8*)&Vt[aoff + mt * 16 * LSTR + ks * 32];
                oacc[mt] = __builtin_amdgcn_mfma_f32_16x16x32_f16(av, bp, oacc[mt], 0, 0, 0);
            }
        }
    }

    // ---- epilogue: lane owns q = q0 + wv*16 + n16, d = mt*16 + quad*4 + r ----
    float inv = 1.0f / l_st;
    float4* out4 = (float4*)out;
    size_t rowbase = (size_t)((b * NH + h) * SEQ + q0 + wv * 16 + n16) * 16;
    #pragma unroll
    for (int mt = 0; mt < 4; ++mt) {
        float4 st = make_float4(oacc[mt][0] * inv, oacc[mt][1] * inv,
                                oacc[mt][2] * inv, oacc[mt][3] * inv);
        out4[rowbase + mt * 4 + quad] = st;
    }
}

extern "C" void kernel_launch(void* const* d_in, const int* in_sizes, int n_in,
                              void* d_out, int out_size, void* d_ws, size_t ws_size,
                              hipStream_t stream) {
    const float* QKV     = (const float*)d_in[0];
    const float* q_scale = (const float*)d_in[1];
    const float* q_bias  = (const float*)d_in[2];
    const float* k_scale = (const float*)d_in[3];
    const float* k_bias  = (const float*)d_in[4];
    float* out = (float*)d_out;

    dim3 grid(SEQ / TQ, NH, NB);  // 32 x 12 x 4 = 1536 blocks
    fused_ln_attn_mfma<<<grid, 256, 0, stream>>>(
        QKV, q_scale, q_bias, k_scale, k_bias, out);
}